// Round 7
// baseline (317.757 us; speedup 1.0000x reference)
//
#include <hip/hip_runtime.h>

static constexpr int B_ROWS = 1048576;
static constexpr int T_LEN  = 32;
static constexpr int NTHR   = 256;
static constexpr int NCHUNK = B_ROWS / NTHR;         // 4096 chunks of 256 rows
static constexpr int NBLK_MAX = 4096;                // partials: 32 KB in d_ws

// float4 with 4-byte alignment: lets the backend emit global_load_dwordx4
// on the 52 B-strided Y rows (dword alignment is sufficient on CDNA).
typedef float f32x4 __attribute__((ext_vector_type(4)));
typedef f32x4 f32x4_a4 __attribute__((aligned(4)));

// One HMM step in f32, fully static indexing, select-form, NO alive tracking:
// NaN obs -> sentinel code 6 with emissions (1,1,1). Each T row sums to 1, so
// a pure-T step preserves sum(alpha) exactly -> log(sum) unchanged by dead
// steps (up to f32 rounding), matching the frozen-alpha reference semantics.
#define HMM_STEP(OF) {                                                        \
    const float of_ = (OF);                                                   \
    const int o = (of_ == of_) ? (int)of_ : 6;                                \
    const float e0f = (o==0)?fy0:(o==1)?fy1:(o==2)?fy2:(o==3)?fr03:(o==6)?1.0f:0.0f; \
    const float e2f = (o==0)?fy4:(o==1)?fy5:(o==2)?fy6:(o==3)?fr23:(o==6)?1.0f:0.0f; \
    const float e1f = (o==4)?fy3:(o==5)?fe15:(o==6)?1.0f:0.0f;                \
    const float n0 = (a0*t00 + a1*t10 + a2*t20) * e0f;                        \
    const float n1 = (a0*t01 + a1*t11 + a2*t21) * e1f;                        \
    const float n2 = (a0*t02 + a1*t12 + a2*t22) * e2f;                        \
    a0 = n0; a1 = n1; a2 = n2;                                                \
}

// Power-of-2 rescale every 2 steps. After a row dies, sum is preserved, so
// this self-limits (fires at most a few extra times, exactly compensated by kk).
#define RESCALE {                                                             \
    const float s_ = a0 + a1 + a2;                                            \
    const bool sc = (s_ < 1e-2f);                                             \
    const float m_ = sc ? 0x1p20f : 1.0f;                                     \
    a0 *= m_; a1 *= m_; a2 *= m_;                                             \
    kk += sc ? 1 : 0;                                                         \
}

#define STEP2(A, B) HMM_STEP(A) HMM_STEP(B) RESCALE

__global__ __launch_bounds__(NTHR, 8) void hmm_fwd_kernel(
    const float* __restrict__ Y,
    const float* __restrict__ Yo,
    const int*   __restrict__ Pi0,
    double*      __restrict__ partials,
    int nblk)
{
    // Reference quirk: E[b,1,5] = 1 - Ysa[1,3] for ALL b (batch row 1, col 3).
    const float fe15 = 1.0f - Y[1 * 13 + 3];   // uniform -> scalar load
    const float pi0 = (float)Pi0[0];
    const float pi1 = (float)Pi0[1];
    const float pi2 = (float)Pi0[2];

    double local = 0.0;
    for (int chunk = blockIdx.x; chunk < NCHUNK; chunk += nblk) {
        const int r = chunk * NTHR + threadIdx.x;

        // Obs row: 32 floats, 128B-aligned; all 8 float4 up front.
        const float4* yo4 = reinterpret_cast<const float4*>(Yo + (size_t)r * T_LEN);
        const float4 v0 = yo4[0], v1 = yo4[1], v2 = yo4[2], v3 = yo4[3];
        const float4 v4 = yo4[4], v5 = yo4[5], v6 = yo4[6], v7 = yo4[7];

        // Y row: 13 floats at 52 B stride -> 3 x dwordx4 + 1 dword.
        const float* y = Y + (size_t)r * 13;
        const f32x4_a4 ya = *reinterpret_cast<const f32x4_a4*>(y + 0);
        const f32x4_a4 yb = *reinterpret_cast<const f32x4_a4*>(y + 4);
        const f32x4_a4 yc = *reinterpret_cast<const f32x4_a4*>(y + 8);
        const float    yd = y[12];
        const float fy0 = ya.x, fy1 = ya.y, fy2 = ya.z, fy3 = ya.w;
        const float fy4 = yb.x, fy5 = yb.y, fy6 = yb.z;
        const float fr03 = 1.0f - fy0 - fy1 - fy2;
        const float fr23 = 1.0f - fy4 - fy5 - fy6;
        const float t00 = yb.w, t01 = yc.x;
        const float t10 = yc.y, t11 = yc.z;
        const float t20 = yc.w, t21 = yd;
        const float t02 = 1.0f - t00 - t01;
        const float t12 = 1.0f - t10 - t11;
        const float t22 = 1.0f - t20 - t21;

        // t = 0 init (always valid: length >= 4)
        float a0, a1, a2;
        {
            const int o = (int)v0.x;
            const float e0f = (o==0)?fy0:(o==1)?fy1:(o==2)?fy2:(o==3)?fr03:0.0f;
            const float e2f = (o==0)?fy4:(o==1)?fy5:(o==2)?fy6:(o==3)?fr23:0.0f;
            const float e1f = (o==4)?fy3:(o==5)?fe15:0.0f;
            a0 = pi0 * e0f;
            a1 = pi1 * e1f;
            a2 = pi2 * e2f;
        }
        int kk = 0;

        HMM_STEP(v0.y)            // t=1
        STEP2(v0.z, v0.w)         // t=2,3
        STEP2(v1.x, v1.y)         // 4,5
        STEP2(v1.z, v1.w)         // 6,7
        STEP2(v2.x, v2.y)         // 8,9
        STEP2(v2.z, v2.w)         // 10,11
        STEP2(v3.x, v3.y)         // 12,13
        STEP2(v3.z, v3.w)         // 14,15
        STEP2(v4.x, v4.y)         // 16,17
        STEP2(v4.z, v4.w)         // 18,19
        STEP2(v5.x, v5.y)         // 20,21
        STEP2(v5.z, v5.w)         // 22,23
        STEP2(v6.x, v6.y)         // 24,25
        STEP2(v6.z, v6.w)         // 26,27
        STEP2(v7.x, v7.y)         // 28,29
        STEP2(v7.z, v7.w)         // 30,31

        float asum = a0 + a1 + a2;
        // Guard: exact-0/NaN alpha-sum -> clamp so output stays finite.
        if (!(asum >= 1e-35f)) asum = 1e-35f;
        local += (double)logf(asum)
               - (double)kk * (20.0 * 0.6931471805599453);
    }

    // Block reduction (double): wave shuffle-reduce, then LDS across 4 waves.
    #pragma unroll
    for (int off = 32; off > 0; off >>= 1)
        local += __shfl_down(local, off, 64);
    __shared__ double sred[NTHR / 64];
    const int lane = threadIdx.x & 63;
    const int wv   = threadIdx.x >> 6;
    if (lane == 0) sred[wv] = local;
    __syncthreads();
    if (threadIdx.x == 0) {
        double s = 0.0;
        #pragma unroll
        for (int i = 0; i < NTHR / 64; ++i) s += sred[i];
        partials[blockIdx.x] = s;
    }
}

__global__ __launch_bounds__(256) void hmm_final_kernel(
    const double* __restrict__ partials, float* __restrict__ out, int nblk)
{
    double local = 0.0;
    for (int i = threadIdx.x; i < nblk; i += 256) local += partials[i];
    #pragma unroll
    for (int off = 32; off > 0; off >>= 1)
        local += __shfl_down(local, off, 64);
    __shared__ double sred[4];
    const int lane = threadIdx.x & 63;
    const int wv   = threadIdx.x >> 6;
    if (lane == 0) sred[wv] = local;
    __syncthreads();
    if (threadIdx.x == 0) {
        double s = sred[0] + sred[1] + sred[2] + sred[3];
        out[0] = (float)(-s / (double)B_ROWS);
    }
}

extern "C" void kernel_launch(void* const* d_in, const int* in_sizes, int n_in,
                              void* d_out, int out_size, void* d_ws, size_t ws_size,
                              hipStream_t stream)
{
    // Identify inputs by size rather than trusting order.
    const float* Y   = nullptr;   // (B, 13) f32
    const float* Yo  = nullptr;   // (B, 32) f32 (NaN-masked obs)
    const int*   Pi0 = nullptr;   // (3,) i32
    for (int i = 0; i < n_in; ++i) {
        if (in_sizes[i] == B_ROWS * 13)      Y   = (const float*)d_in[i];
        else if (in_sizes[i] == B_ROWS * 32) Yo  = (const float*)d_in[i];
        else if (in_sizes[i] == 3)           Pi0 = (const int*)d_in[i];
    }

    int nblk = NBLK_MAX;                              // 4096 -> 1 row/thread
    if (ws_size < (size_t)NBLK_MAX * sizeof(double)) {
        nblk = (int)(ws_size / sizeof(double));
        if (nblk < 1) nblk = 1;
    }
    double* partials = (double*)d_ws;

    hmm_fwd_kernel<<<nblk, NTHR, 0, stream>>>(Y, Yo, Pi0, partials, nblk);
    hmm_final_kernel<<<1, 256, 0, stream>>>(partials, (float*)d_out, nblk);
}

// Round 8
// 69.069 us; speedup vs baseline: 4.6006x; 4.6006x over previous
//
#include <hip/hip_runtime.h>

static constexpr int B_ROWS = 1048576;
static constexpr int T_LEN  = 32;
static constexpr int NTHR   = 256;
static constexpr int NCHUNK = B_ROWS / NTHR;         // 4096 chunks of 256 rows
static constexpr int NBLK_MAX = 4096;                // partials: 32 KB in d_ws

// float4 with 4-byte alignment: lets the backend emit global_load_dwordx4
// on the 52 B-strided Y rows (dword alignment is sufficient on CDNA).
typedef float f32x4 __attribute__((ext_vector_type(4)));
typedef f32x4 f32x4_a4 __attribute__((aligned(4)));

// Pack 4 obs floats into 4-bit codes (NaN -> sentinel 6). The float4 dies
// immediately; 32 obs live across the chain as 4 u32 instead of 32 VGPRs.
__device__ __forceinline__ unsigned pk4(const float4 v) {
    const unsigned o0 = (v.x == v.x) ? (unsigned)(int)v.x : 6u;
    const unsigned o1 = (v.y == v.y) ? (unsigned)(int)v.y : 6u;
    const unsigned o2 = (v.z == v.z) ? (unsigned)(int)v.z : 6u;
    const unsigned o3 = (v.w == v.w) ? (unsigned)(int)v.w : 6u;
    return o0 | (o1 << 4) | (o2 << 8) | (o3 << 12);
}
// Static-shift code extract (compiles to one v_bfe_u32).
#define OC(P, I) ((int)(((P) >> (4 * (I))) & 7u))

// One HMM step in f32, fully static indexing, select-form, NO alive tracking:
// code 6 (past end) uses emissions (1,1,1); T rows sum to 1, so a dead step
// preserves sum(alpha) exactly -> same log(sum) as the frozen-alpha reference.
#define HMM_STEP(O) {                                                         \
    const int o = (O);                                                        \
    const float e0f = (o==0)?fy0:(o==1)?fy1:(o==2)?fy2:(o==3)?fr03:(o==6)?1.0f:0.0f; \
    const float e2f = (o==0)?fy4:(o==1)?fy5:(o==2)?fy6:(o==3)?fr23:(o==6)?1.0f:0.0f; \
    const float e1f = (o==4)?fy3:(o==5)?fe15:(o==6)?1.0f:0.0f;                \
    const float n0 = (a0*t00 + a1*t10 + a2*t20) * e0f;                        \
    const float n1 = (a0*t01 + a1*t11 + a2*t21) * e1f;                        \
    const float n2 = (a0*t02 + a1*t12 + a2*t22) * e2f;                        \
    a0 = n0; a1 = n1; a2 = n2;                                                \
}

// Power-of-2 rescale every 2 steps; self-limits after row death (sum
// preserved), exactly compensated by kk.
#define RESCALE {                                                             \
    const float s_ = a0 + a1 + a2;                                            \
    const bool sc = (s_ < 1e-2f);                                             \
    const float m_ = sc ? 0x1p20f : 1.0f;                                     \
    a0 *= m_; a1 *= m_; a2 *= m_;                                             \
    kk += sc ? 1 : 0;                                                         \
}

#define STEP2(A, B) HMM_STEP(A) HMM_STEP(B) RESCALE

__global__ __launch_bounds__(NTHR) void hmm_fwd_kernel(
    const float* __restrict__ Y,
    const float* __restrict__ Yo,
    const int*   __restrict__ Pi0,
    double*      __restrict__ partials,
    int nblk)
{
    // Reference quirk: E[b,1,5] = 1 - Ysa[1,3] for ALL b (batch row 1, col 3).
    const float fe15 = 1.0f - Y[1 * 13 + 3];   // uniform -> scalar load
    const float pi0 = (float)Pi0[0];
    const float pi1 = (float)Pi0[1];
    const float pi2 = (float)Pi0[2];

    double local = 0.0;
    for (int chunk = blockIdx.x; chunk < NCHUNK; chunk += nblk) {
        const int r = chunk * NTHR + threadIdx.x;

        // Obs row: 8x float4, packed immediately to 4 u32 (short live ranges).
        const float4* yo4 = reinterpret_cast<const float4*>(Yo + (size_t)r * T_LEN);
        const float4 v0 = yo4[0], v1 = yo4[1], v2 = yo4[2], v3 = yo4[3];
        const float4 v4 = yo4[4], v5 = yo4[5], v6 = yo4[6], v7 = yo4[7];
        const unsigned P0 = pk4(v0) | (pk4(v1) << 16);
        const unsigned P1 = pk4(v2) | (pk4(v3) << 16);
        const unsigned P2 = pk4(v4) | (pk4(v5) << 16);
        const unsigned P3 = pk4(v6) | (pk4(v7) << 16);

        // Y row: 13 floats -> 3 x dwordx4 + 1 dword.
        const float* y = Y + (size_t)r * 13;
        const f32x4_a4 ya = *reinterpret_cast<const f32x4_a4*>(y + 0);
        const f32x4_a4 yb = *reinterpret_cast<const f32x4_a4*>(y + 4);
        const f32x4_a4 yc = *reinterpret_cast<const f32x4_a4*>(y + 8);
        const float    yd = y[12];
        const float fy0 = ya.x, fy1 = ya.y, fy2 = ya.z, fy3 = ya.w;
        const float fy4 = yb.x, fy5 = yb.y, fy6 = yb.z;
        const float fr03 = 1.0f - fy0 - fy1 - fy2;
        const float fr23 = 1.0f - fy4 - fy5 - fy6;
        const float t00 = yb.w, t01 = yc.x;
        const float t10 = yc.y, t11 = yc.z;
        const float t20 = yc.w, t21 = yd;
        const float t02 = 1.0f - t00 - t01;
        const float t12 = 1.0f - t10 - t11;
        const float t22 = 1.0f - t20 - t21;

        // t = 0 init (always valid: length >= 4)
        float a0, a1, a2;
        {
            const int o = OC(P0, 0);
            const float e0f = (o==0)?fy0:(o==1)?fy1:(o==2)?fy2:(o==3)?fr03:0.0f;
            const float e2f = (o==0)?fy4:(o==1)?fy5:(o==2)?fy6:(o==3)?fr23:0.0f;
            const float e1f = (o==4)?fy3:(o==5)?fe15:0.0f;
            a0 = pi0 * e0f;
            a1 = pi1 * e1f;
            a2 = pi2 * e2f;
        }
        int kk = 0;

        HMM_STEP(OC(P0, 1))                    // t=1
        STEP2(OC(P0, 2), OC(P0, 3))            // t=2,3
        STEP2(OC(P0, 4), OC(P0, 5))            // 4,5
        STEP2(OC(P0, 6), OC(P0, 7))            // 6,7
        STEP2(OC(P1, 0), OC(P1, 1))            // 8,9
        STEP2(OC(P1, 2), OC(P1, 3))            // 10,11
        STEP2(OC(P1, 4), OC(P1, 5))            // 12,13
        STEP2(OC(P1, 6), OC(P1, 7))            // 14,15
        STEP2(OC(P2, 0), OC(P2, 1))            // 16,17
        STEP2(OC(P2, 2), OC(P2, 3))            // 18,19
        STEP2(OC(P2, 4), OC(P2, 5))            // 20,21
        STEP2(OC(P2, 6), OC(P2, 7))            // 22,23
        STEP2(OC(P3, 0), OC(P3, 1))            // 24,25
        STEP2(OC(P3, 2), OC(P3, 3))            // 26,27
        STEP2(OC(P3, 4), OC(P3, 5))            // 28,29
        STEP2(OC(P3, 6), OC(P3, 7))            // 30,31

        float asum = a0 + a1 + a2;
        // Guard: exact-0/NaN alpha-sum -> clamp so output stays finite.
        if (!(asum >= 1e-35f)) asum = 1e-35f;
        local += (double)logf(asum)
               - (double)kk * (20.0 * 0.6931471805599453);
    }

    // Block reduction (double): wave shuffle-reduce, then LDS across 4 waves.
    #pragma unroll
    for (int off = 32; off > 0; off >>= 1)
        local += __shfl_down(local, off, 64);
    __shared__ double sred[NTHR / 64];
    const int lane = threadIdx.x & 63;
    const int wv   = threadIdx.x >> 6;
    if (lane == 0) sred[wv] = local;
    __syncthreads();
    if (threadIdx.x == 0) {
        double s = 0.0;
        #pragma unroll
        for (int i = 0; i < NTHR / 64; ++i) s += sred[i];
        partials[blockIdx.x] = s;
    }
}

__global__ __launch_bounds__(256) void hmm_final_kernel(
    const double* __restrict__ partials, float* __restrict__ out, int nblk)
{
    double local = 0.0;
    for (int i = threadIdx.x; i < nblk; i += 256) local += partials[i];
    #pragma unroll
    for (int off = 32; off > 0; off >>= 1)
        local += __shfl_down(local, off, 64);
    __shared__ double sred[4];
    const int lane = threadIdx.x & 63;
    const int wv   = threadIdx.x >> 6;
    if (lane == 0) sred[wv] = local;
    __syncthreads();
    if (threadIdx.x == 0) {
        double s = sred[0] + sred[1] + sred[2] + sred[3];
        out[0] = (float)(-s / (double)B_ROWS);
    }
}

extern "C" void kernel_launch(void* const* d_in, const int* in_sizes, int n_in,
                              void* d_out, int out_size, void* d_ws, size_t ws_size,
                              hipStream_t stream)
{
    // Identify inputs by size rather than trusting order.
    const float* Y   = nullptr;   // (B, 13) f32
    const float* Yo  = nullptr;   // (B, 32) f32 (NaN-masked obs)
    const int*   Pi0 = nullptr;   // (3,) i32
    for (int i = 0; i < n_in; ++i) {
        if (in_sizes[i] == B_ROWS * 13)      Y   = (const float*)d_in[i];
        else if (in_sizes[i] == B_ROWS * 32) Yo  = (const float*)d_in[i];
        else if (in_sizes[i] == 3)           Pi0 = (const int*)d_in[i];
    }

    int nblk = NBLK_MAX;                              // 4096 -> 1 row/thread
    if (ws_size < (size_t)NBLK_MAX * sizeof(double)) {
        nblk = (int)(ws_size / sizeof(double));
        if (nblk < 1) nblk = 1;
    }
    double* partials = (double*)d_ws;

    hmm_fwd_kernel<<<nblk, NTHR, 0, stream>>>(Y, Yo, Pi0, partials, nblk);
    hmm_final_kernel<<<1, 256, 0, stream>>>(partials, (float*)d_out, nblk);
}

// Round 9
// 39.711 us; speedup vs baseline: 8.0018x; 1.7393x over previous
//
#include <hip/hip_runtime.h>

static constexpr int B_ROWS = 1048576;
static constexpr int T_LEN  = 32;
static constexpr int NTHR   = 256;
static constexpr int NCHUNK = B_ROWS / NTHR;         // 4096 chunks of 256 rows
static constexpr int NBLK_MAX = 4096;                // partials: 32 KB in d_ws

// float4 with 4-byte alignment: lets the backend emit global_load_dwordx4
// on the 52 B-strided Y rows (dword alignment is sufficient on CDNA).
typedef float f32x4 __attribute__((ext_vector_type(4)));
typedef f32x4 f32x4_a4 __attribute__((aligned(4)));

// Pack 4 obs floats into 4-bit codes. fminf(NaN, 6) == 6 (C99 fmin drops the
// NaN operand; v_min_f32 IEEE mode) -> NaN maps to sentinel code 6 in ONE op.
__device__ __forceinline__ unsigned pk4(const float4 v) {
    const unsigned o0 = (unsigned)(int)fminf(v.x, 6.0f);
    const unsigned o1 = (unsigned)(int)fminf(v.y, 6.0f);
    const unsigned o2 = (unsigned)(int)fminf(v.z, 6.0f);
    const unsigned o3 = (unsigned)(int)fminf(v.w, 6.0f);
    return o0 | (o1 << 4) | (o2 << 8) | (o3 << 12);
}
// Static-shift code extract (one v_bfe_u32).
#define OC(P, I) ((int)(((P) >> (4 * (I))) & 7u))

// One HMM step: emission via per-thread LDS table (kills the ~28-op select
// chains). Code 6 (past end) has emissions (1,1,1): T rows sum to 1, so a
// dead step preserves sum(alpha) exactly -> same log(sum) as frozen-alpha.
#define HMM_STEP(O) {                                                        \
    const float4 e = sE[(O)][threadIdx.x];                                   \
    const float n0 = (a0*t00 + a1*t10 + a2*t20) * e.x;                       \
    const float n1 = (a0*t01 + a1*t11 + a2*t21) * e.y;                       \
    const float n2 = (a0*t02 + a1*t12 + a2*t22) * e.z;                       \
    a0 = n0; a1 = n1; a2 = n2;                                               \
}

// Power-of-2 rescale every 2 steps; self-limits after row death (sum
// preserved), exactly compensated by kk.
#define RESCALE {                                                            \
    const float s_ = a0 + a1 + a2;                                           \
    const bool sc = (s_ < 1e-2f);                                            \
    const float m_ = sc ? 0x1p20f : 1.0f;                                    \
    a0 *= m_; a1 *= m_; a2 *= m_;                                            \
    kk += sc ? 1 : 0;                                                        \
}

#define STEP2(A, B) HMM_STEP(A) HMM_STEP(B) RESCALE

__global__ __launch_bounds__(NTHR) void hmm_fwd_kernel(
    const float* __restrict__ Y,
    const float* __restrict__ Yo,
    const int*   __restrict__ Pi0,
    double*      __restrict__ partials,
    int nblk)
{
    // Per-thread emission table, SoA by code: sE[o][tid] -> addr o*4096+tid*16,
    // banks (lane*4)%32 => exactly 2-way aliasing = free. No barrier needed:
    // each thread writes/reads only its own column. 32 KB/block.
    __shared__ float4 sE[8][NTHR];

    // Reference quirk: E[b,1,5] = 1 - Ysa[1,3] for ALL b (batch row 1, col 3).
    const float fe15 = 1.0f - Y[1 * 13 + 3];   // uniform -> scalar load
    const float pi0 = (float)Pi0[0];
    const float pi1 = (float)Pi0[1];
    const float pi2 = (float)Pi0[2];
    const int tid = threadIdx.x;

    double local = 0.0;
    for (int chunk = blockIdx.x; chunk < NCHUNK; chunk += nblk) {
        const int r = chunk * NTHR + tid;

        // Obs row: 8x float4, packed immediately to 4 u32 (short live ranges).
        const float4* yo4 = reinterpret_cast<const float4*>(Yo + (size_t)r * T_LEN);
        const float4 v0 = yo4[0], v1 = yo4[1], v2 = yo4[2], v3 = yo4[3];
        const float4 v4 = yo4[4], v5 = yo4[5], v6 = yo4[6], v7 = yo4[7];
        const unsigned P0 = pk4(v0) | (pk4(v1) << 16);
        const unsigned P1 = pk4(v2) | (pk4(v3) << 16);
        const unsigned P2 = pk4(v4) | (pk4(v5) << 16);
        const unsigned P3 = pk4(v6) | (pk4(v7) << 16);

        // Y row: 13 floats -> 3 x dwordx4 + 1 dword.
        const float* y = Y + (size_t)r * 13;
        const f32x4_a4 ya = *reinterpret_cast<const f32x4_a4*>(y + 0);
        const f32x4_a4 yb = *reinterpret_cast<const f32x4_a4*>(y + 4);
        const f32x4_a4 yc = *reinterpret_cast<const f32x4_a4*>(y + 8);
        const float    yd = y[12];
        const float fy0 = ya.x, fy1 = ya.y, fy2 = ya.z, fy3 = ya.w;
        const float fy4 = yb.x, fy5 = yb.y, fy6 = yb.z;
        const float fr03 = 1.0f - fy0 - fy1 - fy2;
        const float fr23 = 1.0f - fy4 - fy5 - fy6;
        const float t00 = yb.w, t01 = yc.x;
        const float t10 = yc.y, t11 = yc.z;
        const float t20 = yc.w, t21 = yd;
        const float t02 = 1.0f - t00 - t01;
        const float t12 = 1.0f - t10 - t11;
        const float t22 = 1.0f - t20 - t21;

        // Build this row's emission table (7 ds_write_b128, own column only).
        sE[0][tid] = make_float4(fy0,  0.0f, fy4,  0.0f);
        sE[1][tid] = make_float4(fy1,  0.0f, fy5,  0.0f);
        sE[2][tid] = make_float4(fy2,  0.0f, fy6,  0.0f);
        sE[3][tid] = make_float4(fr03, 0.0f, fr23, 0.0f);
        sE[4][tid] = make_float4(0.0f, fy3,  0.0f, 0.0f);
        sE[5][tid] = make_float4(0.0f, fe15, 0.0f, 0.0f);
        sE[6][tid] = make_float4(1.0f, 1.0f, 1.0f, 0.0f);

        // t = 0 init (always valid: length >= 4)
        float a0, a1, a2;
        {
            const float4 e = sE[OC(P0, 0)][tid];
            a0 = pi0 * e.x;
            a1 = pi1 * e.y;
            a2 = pi2 * e.z;
        }
        int kk = 0;

        HMM_STEP(OC(P0, 1))                    // t=1
        STEP2(OC(P0, 2), OC(P0, 3))            // t=2,3
        STEP2(OC(P0, 4), OC(P0, 5))            // 4,5
        STEP2(OC(P0, 6), OC(P0, 7))            // 6,7
        STEP2(OC(P1, 0), OC(P1, 1))            // 8,9
        STEP2(OC(P1, 2), OC(P1, 3))            // 10,11
        STEP2(OC(P1, 4), OC(P1, 5))            // 12,13
        STEP2(OC(P1, 6), OC(P1, 7))            // 14,15
        STEP2(OC(P2, 0), OC(P2, 1))            // 16,17
        STEP2(OC(P2, 2), OC(P2, 3))            // 18,19
        STEP2(OC(P2, 4), OC(P2, 5))            // 20,21
        STEP2(OC(P2, 6), OC(P2, 7))            // 22,23
        STEP2(OC(P3, 0), OC(P3, 1))            // 24,25
        STEP2(OC(P3, 2), OC(P3, 3))            // 26,27
        STEP2(OC(P3, 4), OC(P3, 5))            // 28,29
        STEP2(OC(P3, 6), OC(P3, 7))            // 30,31

        float asum = a0 + a1 + a2;
        // Guard: exact-0/NaN alpha-sum -> clamp so output stays finite.
        if (!(asum >= 1e-35f)) asum = 1e-35f;
        local += (double)logf(asum)
               - (double)kk * (20.0 * 0.6931471805599453);
    }

    // Block reduction (double): wave shuffle-reduce, then LDS across 4 waves.
    #pragma unroll
    for (int off = 32; off > 0; off >>= 1)
        local += __shfl_down(local, off, 64);
    __shared__ double sred[NTHR / 64];
    const int lane = threadIdx.x & 63;
    const int wv   = threadIdx.x >> 6;
    if (lane == 0) sred[wv] = local;
    __syncthreads();
    if (threadIdx.x == 0) {
        double s = 0.0;
        #pragma unroll
        for (int i = 0; i < NTHR / 64; ++i) s += sred[i];
        partials[blockIdx.x] = s;
    }
}

__global__ __launch_bounds__(256) void hmm_final_kernel(
    const double* __restrict__ partials, float* __restrict__ out, int nblk)
{
    double local = 0.0;
    for (int i = threadIdx.x; i < nblk; i += 256) local += partials[i];
    #pragma unroll
    for (int off = 32; off > 0; off >>= 1)
        local += __shfl_down(local, off, 64);
    __shared__ double sred[4];
    const int lane = threadIdx.x & 63;
    const int wv   = threadIdx.x >> 6;
    if (lane == 0) sred[wv] = local;
    __syncthreads();
    if (threadIdx.x == 0) {
        double s = sred[0] + sred[1] + sred[2] + sred[3];
        out[0] = (float)(-s / (double)B_ROWS);
    }
}

extern "C" void kernel_launch(void* const* d_in, const int* in_sizes, int n_in,
                              void* d_out, int out_size, void* d_ws, size_t ws_size,
                              hipStream_t stream)
{
    // Identify inputs by size rather than trusting order.
    const float* Y   = nullptr;   // (B, 13) f32
    const float* Yo  = nullptr;   // (B, 32) f32 (NaN-masked obs)
    const int*   Pi0 = nullptr;   // (3,) i32
    for (int i = 0; i < n_in; ++i) {
        if (in_sizes[i] == B_ROWS * 13)      Y   = (const float*)d_in[i];
        else if (in_sizes[i] == B_ROWS * 32) Yo  = (const float*)d_in[i];
        else if (in_sizes[i] == 3)           Pi0 = (const int*)d_in[i];
    }

    int nblk = NBLK_MAX;                              // 4096 -> 1 row/thread
    if (ws_size < (size_t)NBLK_MAX * sizeof(double)) {
        nblk = (int)(ws_size / sizeof(double));
        if (nblk < 1) nblk = 1;
    }
    double* partials = (double*)d_ws;

    hmm_fwd_kernel<<<nblk, NTHR, 0, stream>>>(Y, Yo, Pi0, partials, nblk);
    hmm_final_kernel<<<1, 256, 0, stream>>>(partials, (float*)d_out, nblk);
}

// Round 10
// 39.649 us; speedup vs baseline: 8.0143x; 1.0016x over previous
//
#include <hip/hip_runtime.h>

static constexpr int B_ROWS = 1048576;
static constexpr int T_LEN  = 32;
static constexpr int NTHR   = 256;
static constexpr int NCHUNK = B_ROWS / NTHR;         // 4096 chunks of 256 rows
static constexpr int NBLK_MAX = 4096;                // partials: 32 KB in d_ws

// float4 with 4-byte alignment: lets the backend emit global_load_dwordx4
// on the 52 B-strided Y rows (dword alignment is sufficient on CDNA).
typedef float f32x4 __attribute__((ext_vector_type(4)));
typedef f32x4 f32x4_a4 __attribute__((aligned(4)));

// Pack 4 obs floats into 4-bit codes. fminf(NaN, 6) == 6 (C99 fmin drops the
// NaN operand) -> NaN maps to sentinel code 6 in ONE op.
__device__ __forceinline__ unsigned pk4(const float4 v) {
    const unsigned o0 = (unsigned)(int)fminf(v.x, 6.0f);
    const unsigned o1 = (unsigned)(int)fminf(v.y, 6.0f);
    const unsigned o2 = (unsigned)(int)fminf(v.z, 6.0f);
    const unsigned o3 = (unsigned)(int)fminf(v.w, 6.0f);
    return o0 | (o1 << 4) | (o2 << 8) | (o3 << 12);
}
// Static-shift code extract (one v_bfe_u32).
#define OC(P, I) ((int)(((P) >> (4 * (I))) & 7u))

// One HMM step: emissions from split LDS tables (float2 e0/e2 + float e1).
// Code 6 (past end) has emissions (1,1,1): T rows sum to 1, so a dead step
// preserves sum(alpha) exactly -> same log(sum) as the frozen-alpha reference.
#define HMM_STEP(O) {                                                        \
    const int o_ = (O);                                                      \
    const float2 exz = sE2[o_][threadIdx.x];                                 \
    const float  e1  = sE1[o_][threadIdx.x];                                 \
    const float n0 = (a0*t00 + a1*t10 + a2*t20) * exz.x;                     \
    const float n1 = (a0*t01 + a1*t11 + a2*t21) * e1;                        \
    const float n2 = (a0*t02 + a1*t12 + a2*t22) * exz.y;                     \
    a0 = n0; a1 = n1; a2 = n2;                                               \
}

// Power-of-2 rescale every 2 steps; self-limits after row death (sum
// preserved), exactly compensated by kk.
#define RESCALE {                                                            \
    const float s_ = a0 + a1 + a2;                                           \
    const bool sc = (s_ < 1e-2f);                                            \
    const float m_ = sc ? 0x1p20f : 1.0f;                                    \
    a0 *= m_; a1 *= m_; a2 *= m_;                                            \
    kk += sc ? 1 : 0;                                                        \
}

#define STEP2(A, B) HMM_STEP(A) HMM_STEP(B) RESCALE

__global__ __launch_bounds__(NTHR) void hmm_fwd_kernel(
    const float* __restrict__ Y,
    const float* __restrict__ Yo,
    const int*   __restrict__ Pi0,
    double*      __restrict__ partials,
    int nblk)
{
    // Split per-thread emission tables, SoA by code. Dense stride-8 (float2)
    // and stride-4 (float) columns -> conflict-free. 21.5 KB/block ->
    // 7 blocks/CU -> 28 waves/CU (87.5% occupancy). No barrier needed:
    // each thread writes/reads only its own column.
    __shared__ float2 sE2[7][NTHR];
    __shared__ float  sE1[7][NTHR];

    // Reference quirk: E[b,1,5] = 1 - Ysa[1,3] for ALL b (batch row 1, col 3).
    const float fe15 = 1.0f - Y[1 * 13 + 3];   // uniform -> scalar load
    const float pi0 = (float)Pi0[0];
    const float pi1 = (float)Pi0[1];
    const float pi2 = (float)Pi0[2];
    const int tid = threadIdx.x;

    double local = 0.0;
    for (int chunk = blockIdx.x; chunk < NCHUNK; chunk += nblk) {
        const int r = chunk * NTHR + tid;

        // Obs row: 8x float4, packed immediately to 4 u32 (short live ranges).
        const float4* yo4 = reinterpret_cast<const float4*>(Yo + (size_t)r * T_LEN);
        const float4 v0 = yo4[0], v1 = yo4[1], v2 = yo4[2], v3 = yo4[3];
        const float4 v4 = yo4[4], v5 = yo4[5], v6 = yo4[6], v7 = yo4[7];
        const unsigned P0 = pk4(v0) | (pk4(v1) << 16);
        const unsigned P1 = pk4(v2) | (pk4(v3) << 16);
        const unsigned P2 = pk4(v4) | (pk4(v5) << 16);
        const unsigned P3 = pk4(v6) | (pk4(v7) << 16);

        // Y row: 13 floats -> 3 x dwordx4 + 1 dword.
        const float* y = Y + (size_t)r * 13;
        const f32x4_a4 ya = *reinterpret_cast<const f32x4_a4*>(y + 0);
        const f32x4_a4 yb = *reinterpret_cast<const f32x4_a4*>(y + 4);
        const f32x4_a4 yc = *reinterpret_cast<const f32x4_a4*>(y + 8);
        const float    yd = y[12];
        const float fy0 = ya.x, fy1 = ya.y, fy2 = ya.z, fy3 = ya.w;
        const float fy4 = yb.x, fy5 = yb.y, fy6 = yb.z;
        const float fr03 = 1.0f - fy0 - fy1 - fy2;
        const float fr23 = 1.0f - fy4 - fy5 - fy6;
        const float t00 = yb.w, t01 = yc.x;
        const float t10 = yc.y, t11 = yc.z;
        const float t20 = yc.w, t21 = yd;
        const float t02 = 1.0f - t00 - t01;
        const float t12 = 1.0f - t10 - t11;
        const float t22 = 1.0f - t20 - t21;

        // Build this row's emission tables (own column only, no barrier).
        sE2[0][tid] = make_float2(fy0,  fy4);
        sE2[1][tid] = make_float2(fy1,  fy5);
        sE2[2][tid] = make_float2(fy2,  fy6);
        sE2[3][tid] = make_float2(fr03, fr23);
        sE2[4][tid] = make_float2(0.0f, 0.0f);
        sE2[5][tid] = make_float2(0.0f, 0.0f);
        sE2[6][tid] = make_float2(1.0f, 1.0f);
        sE1[0][tid] = 0.0f;
        sE1[1][tid] = 0.0f;
        sE1[2][tid] = 0.0f;
        sE1[3][tid] = 0.0f;
        sE1[4][tid] = fy3;
        sE1[5][tid] = fe15;
        sE1[6][tid] = 1.0f;

        // t = 0 init (always valid: length >= 4)
        float a0, a1, a2;
        {
            const int o0 = OC(P0, 0);
            const float2 exz = sE2[o0][tid];
            const float  e1  = sE1[o0][tid];
            a0 = pi0 * exz.x;
            a1 = pi1 * e1;
            a2 = pi2 * exz.y;
        }
        int kk = 0;

        HMM_STEP(OC(P0, 1))                    // t=1
        STEP2(OC(P0, 2), OC(P0, 3))            // t=2,3
        STEP2(OC(P0, 4), OC(P0, 5))            // 4,5
        STEP2(OC(P0, 6), OC(P0, 7))            // 6,7
        STEP2(OC(P1, 0), OC(P1, 1))            // 8,9
        STEP2(OC(P1, 2), OC(P1, 3))            // 10,11
        STEP2(OC(P1, 4), OC(P1, 5))            // 12,13
        STEP2(OC(P1, 6), OC(P1, 7))            // 14,15
        STEP2(OC(P2, 0), OC(P2, 1))            // 16,17
        STEP2(OC(P2, 2), OC(P2, 3))            // 18,19
        STEP2(OC(P2, 4), OC(P2, 5))            // 20,21
        STEP2(OC(P2, 6), OC(P2, 7))            // 22,23
        STEP2(OC(P3, 0), OC(P3, 1))            // 24,25
        STEP2(OC(P3, 2), OC(P3, 3))            // 26,27
        STEP2(OC(P3, 4), OC(P3, 5))            // 28,29
        STEP2(OC(P3, 6), OC(P3, 7))            // 30,31

        float asum = a0 + a1 + a2;
        // Guard: exact-0/NaN alpha-sum -> clamp so output stays finite.
        if (!(asum >= 1e-35f)) asum = 1e-35f;
        local += (double)logf(asum)
               - (double)kk * (20.0 * 0.6931471805599453);
    }

    // Block reduction (double): wave shuffle-reduce, then LDS across 4 waves.
    #pragma unroll
    for (int off = 32; off > 0; off >>= 1)
        local += __shfl_down(local, off, 64);
    __shared__ double sred[NTHR / 64];
    const int lane = threadIdx.x & 63;
    const int wv   = threadIdx.x >> 6;
    if (lane == 0) sred[wv] = local;
    __syncthreads();
    if (threadIdx.x == 0) {
        double s = 0.0;
        #pragma unroll
        for (int i = 0; i < NTHR / 64; ++i) s += sred[i];
        partials[blockIdx.x] = s;
    }
}

__global__ __launch_bounds__(256) void hmm_final_kernel(
    const double* __restrict__ partials, float* __restrict__ out, int nblk)
{
    double local = 0.0;
    for (int i = threadIdx.x; i < nblk; i += 256) local += partials[i];
    #pragma unroll
    for (int off = 32; off > 0; off >>= 1)
        local += __shfl_down(local, off, 64);
    __shared__ double sred[4];
    const int lane = threadIdx.x & 63;
    const int wv   = threadIdx.x >> 6;
    if (lane == 0) sred[wv] = local;
    __syncthreads();
    if (threadIdx.x == 0) {
        double s = sred[0] + sred[1] + sred[2] + sred[3];
        out[0] = (float)(-s / (double)B_ROWS);
    }
}

extern "C" void kernel_launch(void* const* d_in, const int* in_sizes, int n_in,
                              void* d_out, int out_size, void* d_ws, size_t ws_size,
                              hipStream_t stream)
{
    // Identify inputs by size rather than trusting order.
    const float* Y   = nullptr;   // (B, 13) f32
    const float* Yo  = nullptr;   // (B, 32) f32 (NaN-masked obs)
    const int*   Pi0 = nullptr;   // (3,) i32
    for (int i = 0; i < n_in; ++i) {
        if (in_sizes[i] == B_ROWS * 13)      Y   = (const float*)d_in[i];
        else if (in_sizes[i] == B_ROWS * 32) Yo  = (const float*)d_in[i];
        else if (in_sizes[i] == 3)           Pi0 = (const int*)d_in[i];
    }

    int nblk = NBLK_MAX;                              // 4096 -> 1 row/thread
    if (ws_size < (size_t)NBLK_MAX * sizeof(double)) {
        nblk = (int)(ws_size / sizeof(double));
        if (nblk < 1) nblk = 1;
    }
    double* partials = (double*)d_ws;

    hmm_fwd_kernel<<<nblk, NTHR, 0, stream>>>(Y, Yo, Pi0, partials, nblk);
    hmm_final_kernel<<<1, 256, 0, stream>>>(partials, (float*)d_out, nblk);
}